// Round 4
// baseline (161.950 us; speedup 1.0000x reference)
//
#include <hip/hip_runtime.h>
#include <math.h>

#define Nn    64
#define RPB   2
#define NRAYS 16384
#define NEARV 2.0f
#define FARV  6.0f

// ---- DPP wave64 primitives ----
template <int CTRL, int RMASK>
__device__ __forceinline__ float dpp_mv(float x, float ident) {
  return __int_as_float(__builtin_amdgcn_update_dpp(
      __float_as_int(ident), __float_as_int(x), CTRL, RMASK, 0xf, false));
}
template <int CTRL, int RMASK>
__device__ __forceinline__ int dpp_mvi(int x, int ident) {
  return __builtin_amdgcn_update_dpp(ident, x, CTRL, RMASK, 0xf, false);
}
__device__ __forceinline__ float shfl_up1(float x) {   // lane i <- i-1, lane0 keeps
  return __int_as_float(__builtin_amdgcn_update_dpp(
      __float_as_int(x), __float_as_int(x), 0x138, 0xf, 0xf, false));
}
__device__ __forceinline__ float shfl_dn1(float x) {   // lane i <- i+1, lane63 keeps
  return __int_as_float(__builtin_amdgcn_update_dpp(
      __float_as_int(x), __float_as_int(x), 0x130, 0xf, 0xf, false));
}
__device__ __forceinline__ float scan_add_dpp(float x) {
  x += dpp_mv<0x111, 0xf>(x, 0.f);
  x += dpp_mv<0x112, 0xf>(x, 0.f);
  x += dpp_mv<0x114, 0xf>(x, 0.f);
  x += dpp_mv<0x118, 0xf>(x, 0.f);
  x += dpp_mv<0x142, 0xa>(x, 0.f);   // row_bcast:15 -> rows 1,3
  x += dpp_mv<0x143, 0xc>(x, 0.f);   // row_bcast:31 -> rows 2,3
  return x;
}
__device__ __forceinline__ int scan_add_dpp_int(int x) {
  x += dpp_mvi<0x111, 0xf>(x, 0);
  x += dpp_mvi<0x112, 0xf>(x, 0);
  x += dpp_mvi<0x114, 0xf>(x, 0);
  x += dpp_mvi<0x118, 0xf>(x, 0);
  x += dpp_mvi<0x142, 0xa>(x, 0);
  x += dpp_mvi<0x143, 0xc>(x, 0);
  return x;
}
__device__ __forceinline__ float scan_mul_dpp(float x) {
  x *= dpp_mv<0x111, 0xf>(x, 1.f);
  x *= dpp_mv<0x112, 0xf>(x, 1.f);
  x *= dpp_mv<0x114, 0xf>(x, 1.f);
  x *= dpp_mv<0x118, 0xf>(x, 1.f);
  x *= dpp_mv<0x142, 0xa>(x, 1.f);
  x *= dpp_mv<0x143, 0xc>(x, 1.f);
  return x;
}
__device__ __forceinline__ float reduce_add_bcast(float x) {
  x = scan_add_dpp(x);
  return __int_as_float(__builtin_amdgcn_readlane(__float_as_int(x), 63));
}

__device__ __forceinline__ float fast_rcp(float x) { return __builtin_amdgcn_rcpf(x); }
__device__ __forceinline__ float sigmoidf_fast(float x) { return fast_rcp(1.f + __expf(-x)); }

// ---- bitonic sort of 64 keys across the wave (ascending by lane) ----
template <int LEVEL, int D>
__device__ __forceinline__ void bitonic_stage(unsigned& k, int lane) {
  unsigned t;
  if constexpr (D == 32) {
    t = (unsigned)__builtin_amdgcn_ds_bpermute((lane ^ 32) << 2, (int)k);
  } else {
    t = (unsigned)__builtin_amdgcn_ds_swizzle((int)k, (D << 10) | 0x1F);
  }
  const bool bitd = (lane & D) != 0;
  const bool desc = (lane & (1 << LEVEL)) != 0;
  const unsigned mn = (k < t) ? k : t;
  const unsigned mx = (k < t) ? t : k;
  k = (bitd == desc) ? mn : mx;
}
template <int LEVEL, int D>
struct BSort {
  static __device__ __forceinline__ void run(unsigned& k, int lane) {
    bitonic_stage<LEVEL, D>(k, lane);
    if constexpr (D > 1) BSort<LEVEL, D / 2>::run(k, lane);
    else if constexpr (LEVEL < 6) BSort<LEVEL + 1, (1 << LEVEL)>::run(k, lane);
  }
};

// searchsorted(cdf[0..62], u, 'right'); first step (idx=63) can never take -> start at 32
__device__ __forceinline__ int count_le_f(float arr, float x) {
  int cnt = 0;
#pragma unroll
  for (int step = 32; step >= 1; step >>= 1) {
    const int idx = cnt + step - 1;
    const float v = __shfl(arr, idx, 64);
    if (idx < 63 && v <= x) cnt += step;
  }
  return cnt;
}

// #{lanes: arr_lane < x} over a lane-ascending (non-decreasing) array, in [0,64]
__device__ __forceinline__ int count_lt_sorted(float arr, float x) {
  const float v63 = __shfl(arr, 63, 64);
  int cnt = 0;
#pragma unroll
  for (int step = 32; step >= 1; step >>= 1) {
    const int idx = cnt + step - 1;
    const float v = __shfl(arr, idx, 64);
    if (idx < 63 && v < x) cnt += step;
  }
  return (v63 < x) ? 64 : cnt;
}

// MLP out via piecewise-linear scan: h_k(z) = relu(c0_k + z*c1_k) has ONE knee per
// channel; with samples sorted by z, out_j(s) = P0_j(s) + z_s*P1_j(s) where P0/P1
// are prefix sums over channel contributions scattered at each channel's flip
// position. All fp32 (better than the old bf16-split MFMA path). Replaces MFMA,
// A-fragment prep and B-packing entirely.
__global__ __launch_bounds__(RPB * 64, 5) void nerf_fused(
    const float* __restrict__ ray_o, const float* __restrict__ ray_d,
    const float* __restrict__ tform, const float* __restrict__ noise,
    const float* __restrict__ usmp,  const float* __restrict__ W1,
    const float* __restrict__ b1,    const float* __restrict__ W2,
    const float* __restrict__ b2,    float* __restrict__ out) {
  const int wave = threadIdx.x >> 6;
  const int lane = threadIdx.x & 63;
  const int ray  = blockIdx.x * RPB + wave;

  // All LDS wave-private: no __syncthreads anywhere (same-wave in-order LDS).
  __shared__ float    sP  [RPB][2][Nn][8]; // scatter accum: [eval][sample][{P0,P1}x4]
  __shared__ float4   sPk [RPB][2 * Nn];   // payload by ORIGINAL index
  __shared__ unsigned sKey[RPB][2 * Nn];   // merged sorted keys by position
  __shared__ unsigned sHist[RPB][Nn];      // histogram of fine->coarse ranks

  sHist[wave][lane] = 0u;
  {  // zero both eval accumulators (2*64*8 f32 = 256 float4)
    float4* zp = (float4*)&sP[wave][0][0][0];
    const float4 z4 = make_float4(0.f, 0.f, 0.f, 0.f);
    zp[lane] = z4; zp[64 + lane] = z4; zp[128 + lane] = z4; zp[192 + lane] = z4;
  }

  const float o0 = ray_o[ray * 3 + 0], o1 = ray_o[ray * 3 + 1], o2 = ray_o[ray * 3 + 2];
  float d0 = ray_d[ray * 3 + 0], d1 = ray_d[ray * 3 + 1], d2 = ray_d[ray * 3 + 2];
  const float rn = __builtin_amdgcn_rsqf(d0 * d0 + d1 * d1 + d2 * d2);
  d0 *= rn; d1 *= rn; d2 *= rn;

  // channel (=lane) first-layer affine coeffs, kept in registers
  const float w10 = W1[lane], w11 = W1[64 + lane], w12 = W1[128 + lane];
  const float c1k = d0 * w10 + d1 * w11 + d2 * w12;
  const float c0k = o0 * w10 + o1 * w11 + o2 * w12 + b1[lane];

  // channel contributions to the 4 outputs: g[2j] = W2[k][j]*c0, g[2j+1] = W2[k][j]*c1
  const float4 w2r = *reinterpret_cast<const float4*>(W2 + lane * 4);
  float g[8];
  g[0] = w2r.x * c0k; g[1] = w2r.x * c1k;
  g[2] = w2r.y * c0k; g[3] = w2r.y * c1k;
  g[4] = w2r.z * c0k; g[5] = w2r.z * c1k;
  g[6] = w2r.w * c0k; g[7] = w2r.w * c1k;

  // coarse z (strictly increasing in lane); z in [2, 6.07) -> bits monotone
  const float nz = noise[ray * Nn + lane];
  const float z  = NEARV + (FARV - NEARV) * ((float)lane + nz) * (1.0f / Nn);
  const unsigned kc = ((__float_as_uint(z) - 0x40000000u) << 7) | (unsigned)lane;

  // sort the uniforms now: inverse-CDF is monotone, so sorted u => sorted zs
  unsigned ub = __float_as_uint(usmp[ray * Nn + lane]);  // u in [0,1): bits monotone
  BSort<1, 1>::run(ub, lane);
  const float us = __uint_as_float(ub);

  const float b20 = b2[0], b21 = b2[1], b22 = b2[2], b23 = b2[3];

  // relu knee of this channel (only used under c1k!=0 predicates)
  const float zstar = -c0k * fast_rcp(c1k);

  // ---- coarse flip position: #{s : z_s < zstar} via the noise-ladder closed form
  // z_s < z* <=> s + noise_s < t, t = (z*-NEAR)*16
  int sk_c;
  {
    const float tt = (zstar - NEARV) * 16.0f;
    if (!(tt > 0.0f)) sk_c = 0;            // also catches NaN/-inf
    else if (tt >= 64.0f) sk_c = 64;
    else {
      const int f = (int)tt;
      const float nf = __shfl(nz, f, 64);
      sk_c = f + (((float)f + nf < tt) ? 1 : 0);
    }
  }

  // ---- coarse scatter: channel turns on at sk (c1>0) or off at sk (c1<0)
  {
    float* baseC = &sP[wave][0][0][0];
    if (c1k > 0.0f) {
      if (sk_c < 64) {
        float* p = baseC + sk_c * 8;
#pragma unroll
        for (int j = 0; j < 8; ++j) atomicAdd(p + j, g[j]);
      }
    } else if (c1k < 0.0f) {
      if (sk_c > 0) {
#pragma unroll
        for (int j = 0; j < 8; ++j) atomicAdd(baseC + j, g[j]);
        if (sk_c < 64) {
          float* p = baseC + sk_c * 8;
#pragma unroll
          for (int j = 0; j < 8; ++j) atomicAdd(p + j, -g[j]);
        }
      }
    } else if (c0k > 0.0f) {
#pragma unroll
      for (int j = 0; j < 8; ++j) atomicAdd(baseC + j, g[j]);
    }
  }

  // ---- coarse gather + prefix scans -> per-sample outputs (lane = sample)
  float sig, cr, cg, cb;
  {
    const float4 pa = *reinterpret_cast<const float4*>(&sP[wave][0][lane][0]);
    const float4 pb = *reinterpret_cast<const float4*>(&sP[wave][0][lane][4]);
    const float P00 = scan_add_dpp(pa.x), P10 = scan_add_dpp(pa.y);
    const float P01 = scan_add_dpp(pa.z), P11 = scan_add_dpp(pa.w);
    const float P02 = scan_add_dpp(pb.x), P12 = scan_add_dpp(pb.y);
    const float P03 = scan_add_dpp(pb.z), P13 = scan_add_dpp(pb.w);
    sig = fmaf(z, P10, P00) + b20;
    cr  = sigmoidf_fast(fmaf(z, P11, P01) + b21);
    cg  = sigmoidf_fast(fmaf(z, P12, P02) + b22);
    cb  = sigmoidf_fast(fmaf(z, P13, P03) + b23);
  }
  sPk[wave][lane] = make_float4(sig, cr, cg, cb);   // coarse payload, orig idx = lane

  // ---- coarse compositing weights + smoothed pdf/cdf ----
  const float zn   = shfl_dn1(z);
  const float dist = (lane == 63) ? 1e10f : (zn - z);
  const float alpha = 1.f - __expf(-fmaxf(sig, 0.f) * dist);
  float cdfreg, binreg;
  {
    const float P  = scan_mul_dpp(1.f - alpha + 1e-10f);
    float Te = shfl_up1(P);
    if (lane == 0) Te = 1.f;
    const float w = alpha * Te;

    const float mxA = fmaxf(shfl_up1(w), w);
    const float mxB = fmaxf(w, shfl_dn1(w));
    const float sm = 0.5f * (mxA + mxB) + 0.01f;

    const float v   = (lane >= 1 && lane <= 62) ? sm : 0.f;
    const float tot = reduce_add_bcast(v);
    const float pdf = v * fast_rcp(tot);
    const float C   = scan_add_dpp(pdf);
    cdfreg = (lane == 0) ? 0.f : C;
    binreg = 0.5f * (z + zn);
  }

  // ---- inverse-CDF sampling on SORTED u: zs is ascending by lane ----
  const int lo_i = count_le_f(cdfreg, us);
  const int below = lo_i - 1;
  const int above = (lo_i < 63) ? lo_i : 62;
  const float cdfb = __shfl(cdfreg, below, 64);
  const float cdfa = __shfl(cdfreg, above, 64);
  const float binb = __shfl(binreg, below, 64);
  const float bina = __shfl(binreg, above, 64);
  float den = cdfa - cdfb;
  if (den < 1e-5f) den = 1.f;
  const float zs = fmaf((us - cdfb) * fast_rcp(den), bina - binb, binb);

  // ---- O(1) cross-rank of zs among coarse z (R2 machinery, unchanged)
  const float zb1 = __shfl(z, below + 1, 64);
  const int   cj  = below + 1 + ((zb1 <= zs) ? 1 : 0);   // in [1, 63]
  const int   pos_f = lane + cj;                          // merged position of fine sample
  const unsigned kf = ((__float_as_uint(zs) - 0x40000000u) << 7) | (unsigned)(64 + lane);

  atomicAdd(&sHist[wave][cj], 1u);        // hist[c] = #{fine : cj == c}

  // ---- fine flip position: binary search over the sorted zs array
  const int sk_f = count_lt_sorted(zs, zstar);

  // ---- fine scatter (same predicates, eval slot 1)
  {
    float* baseF = &sP[wave][1][0][0];
    if (c1k > 0.0f) {
      if (sk_f < 64) {
        float* p = baseF + sk_f * 8;
#pragma unroll
        for (int j = 0; j < 8; ++j) atomicAdd(p + j, g[j]);
      }
    } else if (c1k < 0.0f) {
      if (sk_f > 0) {
#pragma unroll
        for (int j = 0; j < 8; ++j) atomicAdd(baseF + j, g[j]);
        if (sk_f < 64) {
          float* p = baseF + sk_f * 8;
#pragma unroll
          for (int j = 0; j < 8; ++j) atomicAdd(p + j, -g[j]);
        }
      }
    } else if (c0k > 0.0f) {
#pragma unroll
      for (int j = 0; j < 8; ++j) atomicAdd(baseF + j, g[j]);
    }
  }

  // coarse merged position: pos_c(i) = i + prefix_incl(hist)[i]
  const int h    = (int)sHist[wave][lane];
  const int pref = scan_add_dpp_int(h);
  const int pos_c = lane + pref;

  // ---- fine gather + scans -> fine outputs
  float sigF, fr, fg, fb;
  {
    const float4 pa = *reinterpret_cast<const float4*>(&sP[wave][1][lane][0]);
    const float4 pb = *reinterpret_cast<const float4*>(&sP[wave][1][lane][4]);
    const float P00 = scan_add_dpp(pa.x), P10 = scan_add_dpp(pa.y);
    const float P01 = scan_add_dpp(pa.z), P11 = scan_add_dpp(pa.w);
    const float P02 = scan_add_dpp(pb.x), P12 = scan_add_dpp(pb.y);
    const float P03 = scan_add_dpp(pb.z), P13 = scan_add_dpp(pb.w);
    sigF = fmaf(zs, P10, P00) + b20;
    fr   = sigmoidf_fast(fmaf(zs, P11, P01) + b21);
    fg   = sigmoidf_fast(fmaf(zs, P12, P02) + b22);
    fb   = sigmoidf_fast(fmaf(zs, P13, P03) + b23);
  }
  sPk[wave][64 + lane] = make_float4(sigF, fr, fg, fb);  // fine payload, orig idx = 64+lane

  // ---- scatter keys to merged order, then read pairs ----
  sKey[wave][pos_c] = kc;
  sKey[wave][pos_f] = kf;
  const uint2 kk = *reinterpret_cast<const uint2*>(&sKey[wave][2 * lane]);
  const unsigned k0 = kk.x;
  const unsigned k1 = kk.y;

  // decode z (bit-exact) and gather payload by original index
  const float z0 = __uint_as_float((k0 >> 7) + 0x40000000u);
  const float z1 = __uint_as_float((k1 >> 7) + 0x40000000u);
  const float4 q0 = sPk[wave][k0 & 127u];
  const float4 q1 = sPk[wave][k1 & 127u];

  // ---- final compositing over 128 sorted samples (2 per lane) ----
  const float z2 = shfl_dn1(z0);
  const float dist0 = z1 - z0;
  const float dist1 = (lane == 63) ? 1e10f : (z2 - z1);
  const float al0 = 1.f - __expf(-fmaxf(q0.x, 0.f) * dist0);
  const float al1 = 1.f - __expf(-fmaxf(q1.x, 0.f) * dist1);
  const float aa0 = 1.f - al0 + 1e-10f;
  const float aa1 = 1.f - al1 + 1e-10f;
  const float Pp = scan_mul_dpp(aa0 * aa1);
  float Tp = shfl_up1(Pp);
  if (lane == 0) Tp = 1.f;
  const float w0 = al0 * Tp;
  const float w1 = al1 * Tp * aa0;

  const float accR = reduce_add_bcast(w0 * q0.y + w1 * q1.y);
  const float accG = reduce_add_bcast(w0 * q0.z + w1 * q1.z);
  const float accB = reduce_add_bcast(w0 * q0.w + w1 * q1.w);
  const float accD = reduce_add_bcast(w0 * z0 + w1 * z1);
  const float accM = reduce_add_bcast(w0 + w1);

  if (lane == 0) {
    const float* tf = tform + (ray >> 12) * 16;
    const float vz = d0 * tf[2] + d1 * tf[6] + d2 * tf[10];
    out[ray * 3 + 0]     = accR;
    out[ray * 3 + 1]     = accG;
    out[ray * 3 + 2]     = accB;
    out[NRAYS * 3 + ray] = -vz * accD;
    out[NRAYS * 4 + ray] = accM;
  }
}

extern "C" void kernel_launch(void* const* d_in, const int* in_sizes, int n_in,
                              void* d_out, int out_size, void* d_ws, size_t ws_size,
                              hipStream_t stream) {
  const float* ray_o = (const float*)d_in[0];
  const float* ray_d = (const float*)d_in[1];
  const float* tform = (const float*)d_in[2];
  const float* noise = (const float*)d_in[3];
  const float* usmp  = (const float*)d_in[4];
  const float* W1    = (const float*)d_in[5];
  const float* b1    = (const float*)d_in[6];
  const float* W2    = (const float*)d_in[7];
  const float* b2    = (const float*)d_in[8];
  float* out = (float*)d_out;

  nerf_fused<<<dim3(NRAYS / RPB), RPB * 64, 0, stream>>>(
      ray_o, ray_d, tform, noise, usmp, W1, b1, W2, b2, out);
}

// Round 5
// 102.917 us; speedup vs baseline: 1.5736x; 1.5736x over previous
//
#include <hip/hip_runtime.h>
#include <hip/hip_bf16.h>
#include <math.h>

#define Nn    64
#define RPB   2
#define NRAYS 16384
#define NEARV 2.0f
#define FARV  6.0f

typedef __attribute__((ext_vector_type(8))) short bf16x8;
typedef __attribute__((ext_vector_type(4))) float f32x4;
typedef __attribute__((ext_vector_type(2))) float f32x2;

// ---- DPP wave64 primitives ----
template <int CTRL, int RMASK>
__device__ __forceinline__ float dpp_mv(float x, float ident) {
  return __int_as_float(__builtin_amdgcn_update_dpp(
      __float_as_int(ident), __float_as_int(x), CTRL, RMASK, 0xf, false));
}
template <int CTRL, int RMASK>
__device__ __forceinline__ int dpp_mvi(int x, int ident) {
  return __builtin_amdgcn_update_dpp(ident, x, CTRL, RMASK, 0xf, false);
}
__device__ __forceinline__ float shfl_up1(float x) {   // lane i <- i-1, lane0 keeps
  return __int_as_float(__builtin_amdgcn_update_dpp(
      __float_as_int(x), __float_as_int(x), 0x138, 0xf, 0xf, false));
}
__device__ __forceinline__ float shfl_dn1(float x) {   // lane i <- i+1, lane63 keeps
  return __int_as_float(__builtin_amdgcn_update_dpp(
      __float_as_int(x), __float_as_int(x), 0x130, 0xf, 0xf, false));
}
__device__ __forceinline__ float scan_add_dpp(float x) {
  x += dpp_mv<0x111, 0xf>(x, 0.f);
  x += dpp_mv<0x112, 0xf>(x, 0.f);
  x += dpp_mv<0x114, 0xf>(x, 0.f);
  x += dpp_mv<0x118, 0xf>(x, 0.f);
  x += dpp_mv<0x142, 0xa>(x, 0.f);   // row_bcast:15 -> rows 1,3
  x += dpp_mv<0x143, 0xc>(x, 0.f);   // row_bcast:31 -> rows 2,3
  return x;
}
__device__ __forceinline__ int scan_add_dpp_int(int x) {
  x += dpp_mvi<0x111, 0xf>(x, 0);
  x += dpp_mvi<0x112, 0xf>(x, 0);
  x += dpp_mvi<0x114, 0xf>(x, 0);
  x += dpp_mvi<0x118, 0xf>(x, 0);
  x += dpp_mvi<0x142, 0xa>(x, 0);
  x += dpp_mvi<0x143, 0xc>(x, 0);
  return x;
}
__device__ __forceinline__ float scan_mul_dpp(float x) {
  x *= dpp_mv<0x111, 0xf>(x, 1.f);
  x *= dpp_mv<0x112, 0xf>(x, 1.f);
  x *= dpp_mv<0x114, 0xf>(x, 1.f);
  x *= dpp_mv<0x118, 0xf>(x, 1.f);
  x *= dpp_mv<0x142, 0xa>(x, 1.f);
  x *= dpp_mv<0x143, 0xc>(x, 1.f);
  return x;
}
__device__ __forceinline__ float reduce_add_bcast(float x) {
  x = scan_add_dpp(x);
  return __int_as_float(__builtin_amdgcn_readlane(__float_as_int(x), 63));
}

__device__ __forceinline__ float fast_rcp(float x) { return __builtin_amdgcn_rcpf(x); }
__device__ __forceinline__ float sigmoidf_fast(float x) { return fast_rcp(1.f + __expf(-x)); }

__device__ __forceinline__ short bfhi_bits(float x) { return (short)(__float_as_uint(x) >> 16); }
__device__ __forceinline__ float bfhi_val(float x)  { return __uint_as_float(__float_as_uint(x) & 0xFFFF0000u); }

// ---- bitonic sort of 64 keys across the wave (ascending by lane) ----
template <int LEVEL, int D>
__device__ __forceinline__ void bitonic_stage(unsigned& k, int lane) {
  unsigned t;
  if constexpr (D == 32) {
    t = (unsigned)__builtin_amdgcn_ds_bpermute((lane ^ 32) << 2, (int)k);
  } else {
    t = (unsigned)__builtin_amdgcn_ds_swizzle((int)k, (D << 10) | 0x1F);
  }
  const bool bitd = (lane & D) != 0;
  const bool desc = (lane & (1 << LEVEL)) != 0;
  const unsigned mn = (k < t) ? k : t;
  const unsigned mx = (k < t) ? t : k;
  k = (bitd == desc) ? mn : mx;
}
template <int LEVEL, int D>
struct BSort {
  static __device__ __forceinline__ void run(unsigned& k, int lane) {
    bitonic_stage<LEVEL, D>(k, lane);
    if constexpr (D > 1) BSort<LEVEL, D / 2>::run(k, lane);
    else if constexpr (LEVEL < 6) BSort<LEVEL + 1, (1 << LEVEL)>::run(k, lane);
  }
};

// searchsorted(cdf[0..62], u, 'right'); first step (idx=63) can never take -> start at 32
__device__ __forceinline__ int count_le_f(float arr, float x) {
  int cnt = 0;
#pragma unroll
  for (int step = 32; step >= 1; step >>= 1) {
    const int idx = cnt + step - 1;
    const float v = __shfl(arr, idx, 64);
    if (idx < 63 && v <= x) cnt += step;
  }
  return cnt;
}

// Field eval, 64 samples/ray: D = W2^T(4x64) @ h^T(64x64) via 16x16x32 bf16 MFMA.
// SPLITB (coarse): trunc split both operands, Ahi*Bhi+Ahi*Blo+Alo*Bhi (exact R4 numerics).
// !SPLITB (fine): B single RNE, Ahi*B + Alo*B (fine feeds only the final composite).
// c0/c1 coeffs are re-read from wave-private LDS (broadcast within each quad, free)
// instead of being held in 32 VGPRs across the whole kernel -> fits the 85-VGPR cap
// of 6 waves/SIMD.
template <bool SPLITB>
__device__ __forceinline__ void field_eval(
    float zlane, const float4* cc4,
    const bf16x8 aHi[2], const bf16x8 aLo[2],
    float b20, float b21, float b22, float b23,
    int quad, int col, float4* scratch, float o[4]) {
#pragma unroll
  for (int nt = 0; nt < 4; ++nt) {
    f32x4 acc = {0.f, 0.f, 0.f, 0.f};
    const float zm = __shfl(zlane, nt * 16 + col, 64);
    const f32x2 zm2 = {zm, zm};
#pragma unroll
    for (int ks = 0; ks < 2; ++ks) {
      const int base4 = (ks * 32 + quad * 8) >> 1;
      union { bf16x8 v; unsigned u[4]; } Bhi, Blo;
#pragma unroll
      for (int p = 0; p < 4; ++p) {
        const float4 cv = cc4[base4 + p];                    // ds_read_b128, quad-broadcast
        const f32x2 c0 = {cv.x, cv.z};
        const f32x2 c1 = {cv.y, cv.w};
        f32x2 h = zm2 * c1 + c0;                             // v_pk_fma_f32
        h = __builtin_elementwise_max(h, (f32x2){0.f, 0.f}); // v_pk_max_f32
        if constexpr (SPLITB) {
          union { f32x2 f; unsigned u[2]; } U; U.f = h;
          Bhi.u[p] = __builtin_amdgcn_perm(U.u[1], U.u[0], 0x07060302u);
          union { unsigned u[2]; f32x2 f; } M;
          M.u[0] = U.u[0] & 0xFFFF0000u;
          M.u[1] = U.u[1] & 0xFFFF0000u;
          const f32x2 l = h - M.f;
          union { f32x2 f; unsigned u[2]; } L; L.f = l;
          Blo.u[p] = __builtin_amdgcn_perm(L.u[1], L.u[0], 0x07060302u);
        } else {
          __hip_bfloat162 t = __float22bfloat162_rn(make_float2(h[0], h[1]));
          Bhi.u[p] = *reinterpret_cast<unsigned*>(&t);
        }
      }
      if constexpr (SPLITB) {
        acc = __builtin_amdgcn_mfma_f32_16x16x32_bf16(aHi[ks], Bhi.v, acc, 0, 0, 0);
        acc = __builtin_amdgcn_mfma_f32_16x16x32_bf16(aHi[ks], Blo.v, acc, 0, 0, 0);
        acc = __builtin_amdgcn_mfma_f32_16x16x32_bf16(aLo[ks], Bhi.v, acc, 0, 0, 0);
      } else {
        acc = __builtin_amdgcn_mfma_f32_16x16x32_bf16(aHi[ks], Bhi.v, acc, 0, 0, 0);
        acc = __builtin_amdgcn_mfma_f32_16x16x32_bf16(aLo[ks], Bhi.v, acc, 0, 0, 0);
      }
    }
    if (quad == 0) scratch[nt * 16 + col] = make_float4(acc[0], acc[1], acc[2], acc[3]);
  }
  const float4 r = scratch[(threadIdx.x & 63)];  // same-wave LDS ordering
  o[0] = r.x + b20; o[1] = r.y + b21; o[2] = r.z + b22; o[3] = r.w + b23;
}

// launch_bounds min-waves/EU = 6 -> VGPR cap 85 (floor(512/6)). c0v/c1v de-hoisted
// to LDS re-reads; estimated peak live ~81 VGPR -> 6 waves/SIMD (+20% vs R3).
__global__ __launch_bounds__(RPB * 64, 6) void nerf_fused(
    const float* __restrict__ ray_o, const float* __restrict__ ray_d,
    const float* __restrict__ tform, const float* __restrict__ noise,
    const float* __restrict__ usmp,  const float* __restrict__ W1,
    const float* __restrict__ b1,    const float* __restrict__ W2,
    const float* __restrict__ b2,    float* __restrict__ out) {
  const int wave = threadIdx.x >> 6;
  const int lane = threadIdx.x & 63;
  const int ray  = blockIdx.x * RPB + wave;
  const int quad = lane >> 4;
  const int col  = lane & 15;

  // All LDS wave-private: no __syncthreads anywhere (same-wave in-order LDS).
  __shared__ float2   sC  [RPB][Nn];
  __shared__ float4   sPk [RPB][2 * Nn];  // payload by ORIGINAL index; [64..127] doubles as eval scratch
  __shared__ unsigned sKey[RPB][2 * Nn];  // merged sorted keys by position
  __shared__ unsigned sHist[RPB][Nn];     // histogram of fine->coarse ranks

  sHist[wave][lane] = 0u;                 // long before the atomics need it

  const float o0 = ray_o[ray * 3 + 0], o1 = ray_o[ray * 3 + 1], o2 = ray_o[ray * 3 + 2];
  float d0 = ray_d[ray * 3 + 0], d1 = ray_d[ray * 3 + 1], d2 = ray_d[ray * 3 + 2];
  const float rn = __builtin_amdgcn_rsqf(d0 * d0 + d1 * d1 + d2 * d2);
  d0 *= rn; d1 *= rn; d2 *= rn;

  {
    const float w10 = W1[lane], w11 = W1[64 + lane], w12 = W1[128 + lane];
    const float c1 = d0 * w10 + d1 * w11 + d2 * w12;
    const float c0 = o0 * w10 + o1 * w11 + o2 * w12 + b1[lane];
    sC[wave][lane] = make_float2(c0, c1);
  }

  // coarse z (strictly increasing in lane); z in [2, 6.07) -> bits monotone
  const float nz = noise[ray * Nn + lane];
  const float z  = NEARV + (FARV - NEARV) * ((float)lane + nz) * (1.0f / Nn);
  const unsigned kc = ((__float_as_uint(z) - 0x40000000u) << 7) | (unsigned)lane;

  // ---- sort the uniforms NOW: inverse-CDF is monotone, so sorted u => sorted zs.
  // 21-stage bitonic runs on the LDS pipe and overlaps the MFMA/VALU coarse eval below.
  unsigned ub = __float_as_uint(usmp[ray * Nn + lane]);  // u in [0,1): bits monotone
  BSort<1, 1>::run(ub, lane);
  const float us = __uint_as_float(ub);

  const float4* cc4 = (const float4*)&sC[wave][0];

  bf16x8 aHi[2], aLo[2];
#pragma unroll
  for (int ks = 0; ks < 2; ++ks) {
#pragma unroll
    for (int j = 0; j < 8; ++j) {
      const int k = ks * 32 + quad * 8 + j;
      const float wv  = (col < 4) ? W2[k * 4 + col] : 0.f;
      aHi[ks][j] = bfhi_bits(wv);
      aLo[ks][j] = bfhi_bits(wv - bfhi_val(wv));
    }
  }
  const float b20 = b2[0], b21 = b2[1], b22 = b2[2], b23 = b2[3];
  float4* scratch = &sPk[wave][64];

  // ---- coarse field eval (exact split numerics) ----
  float oc[4];
  field_eval<true>(z, cc4, aHi, aLo, b20, b21, b22, b23, quad, col, scratch, oc);
  const float sig = oc[0];
  const float cr = sigmoidf_fast(oc[1]), cg = sigmoidf_fast(oc[2]), cb = sigmoidf_fast(oc[3]);
  sPk[wave][lane] = make_float4(sig, cr, cg, cb);   // coarse payload, orig idx = lane

  // ---- coarse compositing weights + smoothed pdf/cdf ----
  const float zn   = shfl_dn1(z);
  const float dist = (lane == 63) ? 1e10f : (zn - z);
  const float alpha = 1.f - __expf(-fmaxf(sig, 0.f) * dist);
  float cdfreg, binreg;
  {
    const float P  = scan_mul_dpp(1.f - alpha + 1e-10f);
    float Te = shfl_up1(P);
    if (lane == 0) Te = 1.f;
    const float w = alpha * Te;

    const float mxA = fmaxf(shfl_up1(w), w);
    const float mxB = fmaxf(w, shfl_dn1(w));
    const float sm = 0.5f * (mxA + mxB) + 0.01f;

    const float v   = (lane >= 1 && lane <= 62) ? sm : 0.f;
    const float tot = reduce_add_bcast(v);
    const float pdf = v * fast_rcp(tot);
    const float C   = scan_add_dpp(pdf);
    cdfreg = (lane == 0) ? 0.f : C;
    binreg = 0.5f * (z + zn);
  }

  // ---- inverse-CDF sampling on SORTED u: zs is ascending by lane ----
  const int lo_i = count_le_f(cdfreg, us);
  const int below = lo_i - 1;
  const int above = (lo_i < 63) ? lo_i : 62;
  const float cdfb = __shfl(cdfreg, below, 64);
  const float cdfa = __shfl(cdfreg, above, 64);
  const float binb = __shfl(binreg, below, 64);
  const float bina = __shfl(binreg, above, 64);
  float den = cdfa - cdfb;
  if (den < 1e-5f) den = 1.f;
  const float zs = fmaf((us - cdfb) * fast_rcp(den), bina - binb, binb);

  // ---- O(1) cross-rank of zs among coarse z: zs in [zmid[below], zmid[above]]
  // so only z[below+1] is undecided. cj = #{i : z_i <= zs} (ties -> coarse first).
  const float zb1 = __shfl(z, below + 1, 64);
  const int   cj  = below + 1 + ((zb1 <= zs) ? 1 : 0);   // in [1, 63]
  const int   pos_f = lane + cj;                          // merged position of fine sample
  const unsigned kf = ((__float_as_uint(zs) - 0x40000000u) << 7) | (unsigned)(64 + lane);

  atomicAdd(&sHist[wave][cj], 1u);        // hist[c] = #{fine : cj == c}

  // ---- fine field eval (A-split only, B single RNE) — overlaps hist latency ----
  float of[4];
  field_eval<false>(zs, cc4, aHi, aLo, b20, b21, b22, b23, quad, col, scratch, of);

  // coarse merged position: pos_c(i) = i + #{fine : zs < z_i} = i + prefix_incl(hist)[i]
  const int h    = (int)sHist[wave][lane];
  const int pref = scan_add_dpp_int(h);
  const int pos_c = lane + pref;

  const float sigF = of[0];
  const float fr = sigmoidf_fast(of[1]), fg = sigmoidf_fast(of[2]), fb = sigmoidf_fast(of[3]);
  sPk[wave][64 + lane] = make_float4(sigF, fr, fg, fb);  // fine payload, orig idx = 64+lane

  // ---- scatter keys to merged order, then read pairs ----
  sKey[wave][pos_c] = kc;
  sKey[wave][pos_f] = kf;
  const uint2 kk = *reinterpret_cast<const uint2*>(&sKey[wave][2 * lane]);
  const unsigned k0 = kk.x;
  const unsigned k1 = kk.y;

  // decode z (bit-exact) and gather payload by original index
  const float z0 = __uint_as_float((k0 >> 7) + 0x40000000u);
  const float z1 = __uint_as_float((k1 >> 7) + 0x40000000u);
  const float4 q0 = sPk[wave][k0 & 127u];
  const float4 q1 = sPk[wave][k1 & 127u];

  // ---- final compositing over 128 sorted samples (2 per lane) ----
  const float z2 = shfl_dn1(z0);
  const float dist0 = z1 - z0;
  const float dist1 = (lane == 63) ? 1e10f : (z2 - z1);
  const float al0 = 1.f - __expf(-fmaxf(q0.x, 0.f) * dist0);
  const float al1 = 1.f - __expf(-fmaxf(q1.x, 0.f) * dist1);
  const float aa0 = 1.f - al0 + 1e-10f;
  const float aa1 = 1.f - al1 + 1e-10f;
  const float Pp = scan_mul_dpp(aa0 * aa1);
  float Tp = shfl_up1(Pp);
  if (lane == 0) Tp = 1.f;
  const float w0 = al0 * Tp;
  const float w1 = al1 * Tp * aa0;

  const float accR = reduce_add_bcast(w0 * q0.y + w1 * q1.y);
  const float accG = reduce_add_bcast(w0 * q0.z + w1 * q1.z);
  const float accB = reduce_add_bcast(w0 * q0.w + w1 * q1.w);
  const float accD = reduce_add_bcast(w0 * z0 + w1 * z1);
  const float accM = reduce_add_bcast(w0 + w1);

  if (lane == 0) {
    const float* tf = tform + (ray >> 12) * 16;
    const float vz = d0 * tf[2] + d1 * tf[6] + d2 * tf[10];
    out[ray * 3 + 0]     = accR;
    out[ray * 3 + 1]     = accG;
    out[ray * 3 + 2]     = accB;
    out[NRAYS * 3 + ray] = -vz * accD;
    out[NRAYS * 4 + ray] = accM;
  }
}

extern "C" void kernel_launch(void* const* d_in, const int* in_sizes, int n_in,
                              void* d_out, int out_size, void* d_ws, size_t ws_size,
                              hipStream_t stream) {
  const float* ray_o = (const float*)d_in[0];
  const float* ray_d = (const float*)d_in[1];
  const float* tform = (const float*)d_in[2];
  const float* noise = (const float*)d_in[3];
  const float* usmp  = (const float*)d_in[4];
  const float* W1    = (const float*)d_in[5];
  const float* b1    = (const float*)d_in[6];
  const float* W2    = (const float*)d_in[7];
  const float* b2    = (const float*)d_in[8];
  float* out = (float*)d_out;

  nerf_fused<<<dim3(NRAYS / RPB), RPB * 64, 0, stream>>>(
      ray_o, ray_d, tform, noise, usmp, W1, b1, W2, b2, out);
}

// Round 6
// 100.424 us; speedup vs baseline: 1.6127x; 1.0248x over previous
//
#include <hip/hip_runtime.h>
#include <hip/hip_bf16.h>
#include <math.h>

#define Nn    64
#define RPB   2
#define NRAYS 16384
#define NEARV 2.0f
#define FARV  6.0f

typedef __attribute__((ext_vector_type(8))) short bf16x8;
typedef __attribute__((ext_vector_type(4))) float f32x4;
typedef __attribute__((ext_vector_type(2))) float f32x2;

// ---- DPP wave64 primitives ----
template <int CTRL, int RMASK>
__device__ __forceinline__ float dpp_mv(float x, float ident) {
  return __int_as_float(__builtin_amdgcn_update_dpp(
      __float_as_int(ident), __float_as_int(x), CTRL, RMASK, 0xf, false));
}
template <int CTRL, int RMASK>
__device__ __forceinline__ int dpp_mvi(int x, int ident) {
  return __builtin_amdgcn_update_dpp(ident, x, CTRL, RMASK, 0xf, false);
}
__device__ __forceinline__ float shfl_up1(float x) {   // lane i <- i-1, lane0 keeps
  return __int_as_float(__builtin_amdgcn_update_dpp(
      __float_as_int(x), __float_as_int(x), 0x138, 0xf, 0xf, false));
}
__device__ __forceinline__ float shfl_dn1(float x) {   // lane i <- i+1, lane63 keeps
  return __int_as_float(__builtin_amdgcn_update_dpp(
      __float_as_int(x), __float_as_int(x), 0x130, 0xf, 0xf, false));
}
__device__ __forceinline__ float scan_add_dpp(float x) {
  x += dpp_mv<0x111, 0xf>(x, 0.f);
  x += dpp_mv<0x112, 0xf>(x, 0.f);
  x += dpp_mv<0x114, 0xf>(x, 0.f);
  x += dpp_mv<0x118, 0xf>(x, 0.f);
  x += dpp_mv<0x142, 0xa>(x, 0.f);   // row_bcast:15 -> rows 1,3
  x += dpp_mv<0x143, 0xc>(x, 0.f);   // row_bcast:31 -> rows 2,3
  return x;
}
__device__ __forceinline__ int scan_add_dpp_int(int x) {
  x += dpp_mvi<0x111, 0xf>(x, 0);
  x += dpp_mvi<0x112, 0xf>(x, 0);
  x += dpp_mvi<0x114, 0xf>(x, 0);
  x += dpp_mvi<0x118, 0xf>(x, 0);
  x += dpp_mvi<0x142, 0xa>(x, 0);
  x += dpp_mvi<0x143, 0xc>(x, 0);
  return x;
}
__device__ __forceinline__ float scan_mul_dpp(float x) {
  x *= dpp_mv<0x111, 0xf>(x, 1.f);
  x *= dpp_mv<0x112, 0xf>(x, 1.f);
  x *= dpp_mv<0x114, 0xf>(x, 1.f);
  x *= dpp_mv<0x118, 0xf>(x, 1.f);
  x *= dpp_mv<0x142, 0xa>(x, 1.f);
  x *= dpp_mv<0x143, 0xc>(x, 1.f);
  return x;
}
__device__ __forceinline__ float reduce_add_bcast(float x) {
  x = scan_add_dpp(x);
  return __int_as_float(__builtin_amdgcn_readlane(__float_as_int(x), 63));
}

__device__ __forceinline__ float fast_rcp(float x) { return __builtin_amdgcn_rcpf(x); }
__device__ __forceinline__ float sigmoidf_fast(float x) { return fast_rcp(1.f + __expf(-x)); }

__device__ __forceinline__ short bfhi_bits(float x) { return (short)(__float_as_uint(x) >> 16); }
__device__ __forceinline__ float bfhi_val(float x)  { return __uint_as_float(__float_as_uint(x) & 0xFFFF0000u); }

// ---- bitonic sort of 64 keys across the wave (ascending by lane) ----
template <int LEVEL, int D>
__device__ __forceinline__ void bitonic_stage(unsigned& k, int lane) {
  unsigned t;
  if constexpr (D == 32) {
    t = (unsigned)__builtin_amdgcn_ds_bpermute((lane ^ 32) << 2, (int)k);
  } else {
    t = (unsigned)__builtin_amdgcn_ds_swizzle((int)k, (D << 10) | 0x1F);
  }
  const bool bitd = (lane & D) != 0;
  const bool desc = (lane & (1 << LEVEL)) != 0;
  const unsigned mn = (k < t) ? k : t;
  const unsigned mx = (k < t) ? t : k;
  k = (bitd == desc) ? mn : mx;
}
template <int LEVEL, int D>
struct BSort {
  static __device__ __forceinline__ void run(unsigned& k, int lane) {
    bitonic_stage<LEVEL, D>(k, lane);
    if constexpr (D > 1) BSort<LEVEL, D / 2>::run(k, lane);
    else if constexpr (LEVEL < 6) BSort<LEVEL + 1, (1 << LEVEL)>::run(k, lane);
  }
};

// searchsorted(cdf[0..62], u, 'right'); first step (idx=63) can never take -> start at 32
__device__ __forceinline__ int count_le_f(float arr, float x) {
  int cnt = 0;
#pragma unroll
  for (int step = 32; step >= 1; step >>= 1) {
    const int idx = cnt + step - 1;
    const float v = __shfl(arr, idx, 64);
    if (idx < 63 && v <= x) cnt += step;
  }
  return cnt;
}

// Field eval, 64 samples/ray: D = W2^T(4x64) @ h^T(64x64) via 16x16x32 bf16 MFMA.
// SPLITB (coarse): trunc split both operands, Ahi*Bhi+Ahi*Blo+Alo*Bhi (exact R4 numerics).
// !SPLITB (fine): B single RNE, Ahi*B + Alo*B (fine feeds only the final composite).
template <bool SPLITB>
__device__ __forceinline__ void field_eval(
    float zlane, const f32x2 c0v[2][4], const f32x2 c1v[2][4],
    const bf16x8 aHi[2], const bf16x8 aLo[2],
    float b20, float b21, float b22, float b23,
    int quad, int col, float4* scratch, float o[4]) {
#pragma unroll
  for (int nt = 0; nt < 4; ++nt) {
    f32x4 acc = {0.f, 0.f, 0.f, 0.f};
    const float zm = __shfl(zlane, nt * 16 + col, 64);
    const f32x2 zm2 = {zm, zm};
#pragma unroll
    for (int ks = 0; ks < 2; ++ks) {
      union { bf16x8 v; unsigned u[4]; } Bhi, Blo;
#pragma unroll
      for (int p = 0; p < 4; ++p) {
        f32x2 h = zm2 * c1v[ks][p] + c0v[ks][p];             // v_pk_fma_f32
        h = __builtin_elementwise_max(h, (f32x2){0.f, 0.f}); // v_pk_max_f32
        if constexpr (SPLITB) {
          union { f32x2 f; unsigned u[2]; } U; U.f = h;
          Bhi.u[p] = __builtin_amdgcn_perm(U.u[1], U.u[0], 0x07060302u);
          union { unsigned u[2]; f32x2 f; } M;
          M.u[0] = U.u[0] & 0xFFFF0000u;
          M.u[1] = U.u[1] & 0xFFFF0000u;
          const f32x2 l = h - M.f;
          union { f32x2 f; unsigned u[2]; } L; L.f = l;
          Blo.u[p] = __builtin_amdgcn_perm(L.u[1], L.u[0], 0x07060302u);
        } else {
          __hip_bfloat162 t = __float22bfloat162_rn(make_float2(h[0], h[1]));
          Bhi.u[p] = *reinterpret_cast<unsigned*>(&t);
        }
      }
      if constexpr (SPLITB) {
        acc = __builtin_amdgcn_mfma_f32_16x16x32_bf16(aHi[ks], Bhi.v, acc, 0, 0, 0);
        acc = __builtin_amdgcn_mfma_f32_16x16x32_bf16(aHi[ks], Blo.v, acc, 0, 0, 0);
        acc = __builtin_amdgcn_mfma_f32_16x16x32_bf16(aLo[ks], Bhi.v, acc, 0, 0, 0);
      } else {
        acc = __builtin_amdgcn_mfma_f32_16x16x32_bf16(aHi[ks], Bhi.v, acc, 0, 0, 0);
        acc = __builtin_amdgcn_mfma_f32_16x16x32_bf16(aLo[ks], Bhi.v, acc, 0, 0, 0);
      }
    }
    if (quad == 0) scratch[nt * 16 + col] = make_float4(acc[0], acc[1], acc[2], acc[3]);
  }
  const float4 r = scratch[(threadIdx.x & 63)];  // same-wave LDS ordering
  o[0] = r.x + b20; o[1] = r.y + b21; o[2] = r.z + b22; o[3] = r.w + b23;
}

// launch_bounds min-waves/EU = 5 -> VGPR cap 102: the best-verified config
// (R3: 101.0 us). 6 waves/EU (cap 85) measured neutral-to-worse (R5: 102.9).
__global__ __launch_bounds__(RPB * 64, 5) void nerf_fused(
    const float* __restrict__ ray_o, const float* __restrict__ ray_d,
    const float* __restrict__ tform, const float* __restrict__ noise,
    const float* __restrict__ usmp,  const float* __restrict__ W1,
    const float* __restrict__ b1,    const float* __restrict__ W2,
    const float* __restrict__ b2,    float* __restrict__ out) {
  const int wave = threadIdx.x >> 6;
  const int lane = threadIdx.x & 63;
  const int ray  = blockIdx.x * RPB + wave;
  const int quad = lane >> 4;
  const int col  = lane & 15;

  // All LDS wave-private: no __syncthreads anywhere (same-wave in-order LDS).
  __shared__ float2   sC  [RPB][Nn];
  __shared__ float4   sPk [RPB][2 * Nn];  // payload by ORIGINAL index; [64..127] doubles as eval scratch
  __shared__ unsigned sKey[RPB][2 * Nn];  // merged sorted keys by position
  __shared__ unsigned sHist[RPB][Nn];     // histogram of fine->coarse ranks

  sHist[wave][lane] = 0u;                 // long before the atomics need it

  const float o0 = ray_o[ray * 3 + 0], o1 = ray_o[ray * 3 + 1], o2 = ray_o[ray * 3 + 2];
  float d0 = ray_d[ray * 3 + 0], d1 = ray_d[ray * 3 + 1], d2 = ray_d[ray * 3 + 2];
  const float rn = __builtin_amdgcn_rsqf(d0 * d0 + d1 * d1 + d2 * d2);
  d0 *= rn; d1 *= rn; d2 *= rn;

  {
    const float w10 = W1[lane], w11 = W1[64 + lane], w12 = W1[128 + lane];
    const float c1 = d0 * w10 + d1 * w11 + d2 * w12;
    const float c0 = o0 * w10 + o1 * w11 + o2 * w12 + b1[lane];
    sC[wave][lane] = make_float2(c0, c1);
  }

  // coarse z (strictly increasing in lane); z in [2, 6.07) -> bits monotone
  const float nz = noise[ray * Nn + lane];
  const float z  = NEARV + (FARV - NEARV) * ((float)lane + nz) * (1.0f / Nn);
  const unsigned kc = ((__float_as_uint(z) - 0x40000000u) << 7) | (unsigned)lane;

  // ---- sort the uniforms NOW: inverse-CDF is monotone, so sorted u => sorted zs.
  // 21-stage bitonic runs on the LDS pipe and overlaps the MFMA/VALU coarse eval below.
  unsigned ub = __float_as_uint(usmp[ray * Nn + lane]);  // u in [0,1): bits monotone
  BSort<1, 1>::run(ub, lane);
  const float us = __uint_as_float(ub);

  f32x2 c0v[2][4], c1v[2][4];
#pragma unroll
  for (int ks = 0; ks < 2; ++ks) {
    const float4* cc4 = (const float4*)&sC[wave][0];
    const int base4 = (ks * 32 + quad * 8) >> 1;
#pragma unroll
    for (int jj = 0; jj < 4; ++jj) {
      const float4 v = cc4[base4 + jj];
      c0v[ks][jj] = (f32x2){v.x, v.z};
      c1v[ks][jj] = (f32x2){v.y, v.w};
    }
  }

  bf16x8 aHi[2], aLo[2];
#pragma unroll
  for (int ks = 0; ks < 2; ++ks) {
#pragma unroll
    for (int j = 0; j < 8; ++j) {
      const int k = ks * 32 + quad * 8 + j;
      const float wv  = (col < 4) ? W2[k * 4 + col] : 0.f;
      aHi[ks][j] = bfhi_bits(wv);
      aLo[ks][j] = bfhi_bits(wv - bfhi_val(wv));
    }
  }
  const float b20 = b2[0], b21 = b2[1], b22 = b2[2], b23 = b2[3];
  float4* scratch = &sPk[wave][64];

  // ---- coarse field eval (exact split numerics) ----
  float oc[4];
  field_eval<true>(z, c0v, c1v, aHi, aLo, b20, b21, b22, b23, quad, col, scratch, oc);
  const float sig = oc[0];
  const float cr = sigmoidf_fast(oc[1]), cg = sigmoidf_fast(oc[2]), cb = sigmoidf_fast(oc[3]);
  sPk[wave][lane] = make_float4(sig, cr, cg, cb);   // coarse payload, orig idx = lane

  // ---- coarse compositing weights + smoothed pdf/cdf ----
  const float zn   = shfl_dn1(z);
  const float dist = (lane == 63) ? 1e10f : (zn - z);
  const float alpha = 1.f - __expf(-fmaxf(sig, 0.f) * dist);
  float cdfreg, binreg;
  {
    const float P  = scan_mul_dpp(1.f - alpha + 1e-10f);
    float Te = shfl_up1(P);
    if (lane == 0) Te = 1.f;
    const float w = alpha * Te;

    const float mxA = fmaxf(shfl_up1(w), w);
    const float mxB = fmaxf(w, shfl_dn1(w));
    const float sm = 0.5f * (mxA + mxB) + 0.01f;

    const float v   = (lane >= 1 && lane <= 62) ? sm : 0.f;
    const float tot = reduce_add_bcast(v);
    const float pdf = v * fast_rcp(tot);
    const float C   = scan_add_dpp(pdf);
    cdfreg = (lane == 0) ? 0.f : C;
    binreg = 0.5f * (z + zn);
  }

  // ---- inverse-CDF sampling on SORTED u: zs is ascending by lane ----
  const int lo_i = count_le_f(cdfreg, us);
  const int below = lo_i - 1;
  const int above = (lo_i < 63) ? lo_i : 62;
  const float cdfb = __shfl(cdfreg, below, 64);
  const float cdfa = __shfl(cdfreg, above, 64);
  const float binb = __shfl(binreg, below, 64);
  const float bina = __shfl(binreg, above, 64);
  float den = cdfa - cdfb;
  if (den < 1e-5f) den = 1.f;
  const float zs = fmaf((us - cdfb) * fast_rcp(den), bina - binb, binb);

  // ---- O(1) cross-rank of zs among coarse z: zs in [zmid[below], zmid[above]]
  // so only z[below+1] is undecided. cj = #{i : z_i <= zs} (ties -> coarse first).
  const float zb1 = __shfl(z, below + 1, 64);
  const int   cj  = below + 1 + ((zb1 <= zs) ? 1 : 0);   // in [1, 63]
  const int   pos_f = lane + cj;                          // merged position of fine sample
  const unsigned kf = ((__float_as_uint(zs) - 0x40000000u) << 7) | (unsigned)(64 + lane);

  atomicAdd(&sHist[wave][cj], 1u);        // hist[c] = #{fine : cj == c}

  // ---- fine field eval (A-split only, B single RNE) — overlaps hist latency ----
  float of[4];
  field_eval<false>(zs, c0v, c1v, aHi, aLo, b20, b21, b22, b23, quad, col, scratch, of);

  // coarse merged position: pos_c(i) = i + #{fine : zs < z_i} = i + prefix_incl(hist)[i]
  const int h    = (int)sHist[wave][lane];
  const int pref = scan_add_dpp_int(h);
  const int pos_c = lane + pref;

  const float sigF = of[0];
  const float fr = sigmoidf_fast(of[1]), fg = sigmoidf_fast(of[2]), fb = sigmoidf_fast(of[3]);
  sPk[wave][64 + lane] = make_float4(sigF, fr, fg, fb);  // fine payload, orig idx = 64+lane

  // ---- scatter keys to merged order, then read pairs ----
  sKey[wave][pos_c] = kc;
  sKey[wave][pos_f] = kf;
  const uint2 kk = *reinterpret_cast<const uint2*>(&sKey[wave][2 * lane]);
  const unsigned k0 = kk.x;
  const unsigned k1 = kk.y;

  // decode z (bit-exact) and gather payload by original index
  const float z0 = __uint_as_float((k0 >> 7) + 0x40000000u);
  const float z1 = __uint_as_float((k1 >> 7) + 0x40000000u);
  const float4 q0 = sPk[wave][k0 & 127u];
  const float4 q1 = sPk[wave][k1 & 127u];

  // ---- final compositing over 128 sorted samples (2 per lane) ----
  const float z2 = shfl_dn1(z0);
  const float dist0 = z1 - z0;
  const float dist1 = (lane == 63) ? 1e10f : (z2 - z1);
  const float al0 = 1.f - __expf(-fmaxf(q0.x, 0.f) * dist0);
  const float al1 = 1.f - __expf(-fmaxf(q1.x, 0.f) * dist1);
  const float aa0 = 1.f - al0 + 1e-10f;
  const float aa1 = 1.f - al1 + 1e-10f;
  const float Pp = scan_mul_dpp(aa0 * aa1);
  float Tp = shfl_up1(Pp);
  if (lane == 0) Tp = 1.f;
  const float w0 = al0 * Tp;
  const float w1 = al1 * Tp * aa0;

  const float accR = reduce_add_bcast(w0 * q0.y + w1 * q1.y);
  const float accG = reduce_add_bcast(w0 * q0.z + w1 * q1.z);
  const float accB = reduce_add_bcast(w0 * q0.w + w1 * q1.w);
  const float accD = reduce_add_bcast(w0 * z0 + w1 * z1);
  const float accM = reduce_add_bcast(w0 + w1);

  if (lane == 0) {
    const float* tf = tform + (ray >> 12) * 16;
    const float vz = d0 * tf[2] + d1 * tf[6] + d2 * tf[10];
    out[ray * 3 + 0]     = accR;
    out[ray * 3 + 1]     = accG;
    out[ray * 3 + 2]     = accB;
    out[NRAYS * 3 + ray] = -vz * accD;
    out[NRAYS * 4 + ray] = accM;
  }
}

extern "C" void kernel_launch(void* const* d_in, const int* in_sizes, int n_in,
                              void* d_out, int out_size, void* d_ws, size_t ws_size,
                              hipStream_t stream) {
  const float* ray_o = (const float*)d_in[0];
  const float* ray_d = (const float*)d_in[1];
  const float* tform = (const float*)d_in[2];
  const float* noise = (const float*)d_in[3];
  const float* usmp  = (const float*)d_in[4];
  const float* W1    = (const float*)d_in[5];
  const float* b1    = (const float*)d_in[6];
  const float* W2    = (const float*)d_in[7];
  const float* b2    = (const float*)d_in[8];
  float* out = (float*)d_out;

  nerf_fused<<<dim3(NRAYS / RPB), RPB * 64, 0, stream>>>(
      ray_o, ray_d, tform, noise, usmp, W1, b1, W2, b2, out);
}